// Round 3
// baseline (372.767 us; speedup 1.0000x reference)
//
#include <hip/hip_runtime.h>
#include <math.h>

#define NB 512
#define ND 64
#define EPSF 1e-8f

typedef float v4f __attribute__((ext_vector_type(4)));

// ---------------- Kernel 1: phases + complex linear projections ----------------
__global__ __launch_bounds__(64) void proj_kernel(
    const float* __restrict__ Zq, const float* __restrict__ Zk, const float* __restrict__ Zv,
    const float* __restrict__ tma,
    const float* __restrict__ Wq_w, const float* __restrict__ Wq_b,
    const float* __restrict__ Wk_w, const float* __restrict__ Wk_b,
    const float* __restrict__ Wv_w, const float* __restrict__ Wv_b,
    const float* __restrict__ lam_v,
    float* __restrict__ ef_r, float* __restrict__ ef_i,
    float* __restrict__ Uq_r, float* __restrict__ Uq_i,
    float* __restrict__ Uk_r, float* __restrict__ Uk_i,
    float* __restrict__ Uv_r, float* __restrict__ Uv_i,
    float* __restrict__ Vr_o, float* __restrict__ Vi_o,
    float* __restrict__ sumq, float* __restrict__ sumk,
    float* __restrict__ lam_out)
{
    const int bn = blockIdx.x;          // b*N + n
    const int b  = bn >> 9;
    const int n  = bn & (NB - 1);
    const int d  = threadIdx.x;         // 0..63

    __shared__ float zqr[ND], zqi[ND], zkr[ND], zki[ND], zvr[ND], zvi[ND];
    zqr[d] = Zq[((b*2 + 0)*NB + n)*ND + d];
    zqi[d] = Zq[((b*2 + 1)*NB + n)*ND + d];
    zkr[d] = Zk[((b*2 + 0)*NB + n)*ND + d];
    zki[d] = Zk[((b*2 + 1)*NB + n)*ND + d];
    zvr[d] = Zv[((b*2 + 0)*NB + n)*ND + d];
    zvi[d] = Zv[((b*2 + 1)*NB + n)*ND + d];
    __syncthreads();

    // lam_imag = concat([lam_v, -lam_v])
    const float lam = (d < 32) ? lam_v[d] : -lam_v[d - 32];
    const float t0    = tma[0];
    const float denom = tma[NB - 1] - t0;
    const float tn    = tma[n] / denom;
    const float ph  = tn * lam;
    const float efr = cosf(ph);
    const float efi = sinf(ph);

    if (b == 0) { ef_r[n*ND + d] = efr; ef_i[n*ND + d] = efi; }
    if (bn == 0) { lam_out[d] = 0.0f; lam_out[ND + d] = lam; }

    float qr = Wq_b[d], qi = Wq_b[ND + d];
    float kr = Wk_b[d], ki = Wk_b[ND + d];
    float vr = Wv_b[d], vi = Wv_b[ND + d];
    const int r0 = d * ND;          // W[0][d][:]
    const int r1 = ND*ND + d * ND;  // W[1][d][:]
    #pragma unroll 8
    for (int e = 0; e < ND; ++e) {
        const float w0q = Wq_w[r0 + e], w1q = Wq_w[r1 + e];
        qr += zqr[e]*w0q - zqi[e]*w1q;
        qi += zqr[e]*w1q + zqi[e]*w0q;
        const float w0k = Wk_w[r0 + e], w1k = Wk_w[r1 + e];
        kr += zkr[e]*w0k - zki[e]*w1k;
        ki += zkr[e]*w1k + zki[e]*w0k;
        const float w0v = Wv_w[r0 + e], w1v = Wv_w[r1 + e];
        vr += zvr[e]*w0v - zvi[e]*w1v;
        vi += zvr[e]*w1v + zvi[e]*w0v;
    }

    // U = conj(ef) * X   (eb = ef_r, -ef_i)
    const float uqr = efr*qr + efi*qi, uqi = efr*qi - efi*qr;
    const float ukr = efr*kr + efi*ki, uki = efr*ki - efi*kr;
    const float uvr = efr*vr + efi*vi, uvi = efr*vi - efi*vr;

    const int idx = bn*ND + d;
    Uq_r[idx] = uqr; Uq_i[idx] = uqi;
    Uk_r[idx] = ukr; Uk_i[idx] = uki;
    Uv_r[idx] = uvr; Uv_i[idx] = uvi;
    Vr_o[idx] = vr;  Vi_o[idx] = vi;

    // per-row |Uq|^2, |Uk|^2 sums (W2 = cos^2+sin^2 == 1)
    float q2 = uqr*uqr + uqi*uqi;
    float k2 = ukr*ukr + uki*uki;
    #pragma unroll
    for (int off = 32; off > 0; off >>= 1) {
        q2 += __shfl_down(q2, off);
        k2 += __shfl_down(k2, off);
    }
    if (d == 0) { sumq[bn] = q2; sumk[bn] = k2; }
}

// ---------------- Kernel 2: fused attention + out-projection + Z_ij stream ----------------
// Fusion rationale: the softmax/score phases are latency-bound with an idle
// VMEM pipe; the 256 MB Z_ij store stream (formerly a separate kernel) and
// the tiny output projection now run inside the same block, so store drain
// overlaps score/softmax latency across the 1024 co-resident blocks.
__global__ __launch_bounds__(256) void attn_fused_kernel(
    const float* __restrict__ ef_r, const float* __restrict__ ef_i,
    const float* __restrict__ Uq_r, const float* __restrict__ Uq_i,
    const float* __restrict__ Uk_r, const float* __restrict__ Uk_i,
    const float* __restrict__ Uv_r, const float* __restrict__ Uv_i,
    const float* __restrict__ Vr,  const float* __restrict__ Vi,
    const float* __restrict__ sumq, const float* __restrict__ sumk,
    const float* __restrict__ tma,
    const float* __restrict__ eta_param,
    const float* __restrict__ Wp_w, const float* __restrict__ Wp_b,
    const float* __restrict__ s_lo, const float* __restrict__ s_lg,
    const float* __restrict__ s_nf, const float* __restrict__ s_tau,
    float* __restrict__ estl_out,   // est_latent
    float* __restrict__ out_proj,   // out
    float* __restrict__ Q_out,      // Q_ij
    float* __restrict__ Z_out)      // Z_ij_hat_all (256 MB stream)
{
    const int bi  = blockIdx.x;     // b*N + i
    const int b   = bi >> 9;
    const int i   = bi & (NB - 1);
    const int tid = threadIdx.x;    // 0..255

    __shared__ __align__(16) float sA[NB];
    __shared__ __align__(16) float qr_s[ND], qi_s[ND];
    __shared__ __align__(16) float efr_s[ND], efi_s[ND];
    __shared__ float red[256];
    __shared__ __align__(16) float erp[8][ND];
    __shared__ float pr_s[ND], pi_s[ND];

    const float t0    = tma[0];
    const float denom = tma[NB - 1] - t0;
    const float ti    = tma[i] / denom;
    const float lo    = s_lo[0] * s_lo[0];
    const float lg    = s_lg[0] * s_lg[0] + EPSF;
    const float nf2   = s_nf[0] * s_nf[0] + EPSF;
    const float tau2  = s_tau[0] * s_tau[0];
    const float t1    = sumq[bi];

    if (tid < ND) {
        qr_s[tid] = Uq_r[bi*ND + tid]; qi_s[tid] = Uq_i[bi*ND + tid];
    } else if (tid < 2*ND) {
        const int d = tid - ND;
        efr_s[d] = ef_r[i*ND + d]; efi_s[d] = ef_i[i*ND + d];
    }
    __syncthreads();

    // ---- scores for j <= i ----
    float lmax = -INFINITY;
    for (int j = tid; j <= i; j += 256) {
        const float4* kr4 = (const float4*)&Uk_r[(b*NB + j)*ND];
        const float4* ki4 = (const float4*)&Uk_i[(b*NB + j)*ND];
        const float4* qr4 = (const float4*)qr_s;
        const float4* qi4 = (const float4*)qi_s;
        float dot = 0.0f;
        #pragma unroll
        for (int e = 0; e < ND/4; ++e) {
            const float4 kr = kr4[e], ki = ki4[e];
            const float4 qr = qr4[e], qi = qi4[e];
            dot += qr.x*kr.x + qr.y*kr.y + qr.z*kr.z + qr.w*kr.w
                 + qi.x*ki.x + qi.y*ki.y + qi.z*ki.z + qi.w*ki.w;
        }
        const float tj   = tma[j] / denom;
        const float vavg = lo * fabsf(ti - tj) + lg;
        const float base = nf2 * vavg + t1 + sumk[b*NB + j] - 2.0f*dot;
        const float sc   = -tau2 * logf(base);
        sA[j] = sc;
        lmax = fmaxf(lmax, sc);
    }

    // ---- block max ----
    red[tid] = lmax; __syncthreads();
    for (int s = 128; s > 0; s >>= 1) {
        if (tid < s) red[tid] = fmaxf(red[tid], red[tid + s]);
        __syncthreads();
    }
    const float m = red[0];
    __syncthreads();

    // ---- exp + block sum ----
    float lsum = 0.0f;
    for (int j = tid; j <= i; j += 256) {
        const float e = expf(sA[j] - m);
        sA[j] = e;
        lsum += e;
    }
    red[tid] = lsum; __syncthreads();
    for (int s = 128; s > 0; s >>= 1) {
        if (tid < s) red[tid] += red[tid + s];
        __syncthreads();
    }
    const float inv = 1.0f / red[0];
    __syncthreads();

    // ---- write A row (real plane) + zero imag plane (nontemporal: pure stream) ----
    for (int j = tid; j < NB; j += 256) {
        float a = 0.0f;
        if (j <= i) { a = sA[j] * inv; sA[j] = a; }
        __builtin_nontemporal_store(a,    &Q_out[((size_t)(b*2 + 0)*NB + i)*NB + j]);
        __builtin_nontemporal_store(0.0f, &Q_out[((size_t)(b*2 + 1)*NB + i)*NB + j]);
    }
    __syncthreads();

    // ---- er/ei = A @ Uv ; 4 waves split j, lanes are d ----
    const int lane = tid & 63;
    const int w    = tid >> 6;
    float er = 0.0f, ei = 0.0f;
    for (int j = w; j <= i; j += 4) {
        const float a = sA[j];
        er += a * Uv_r[(b*NB + j)*ND + lane];
        ei += a * Uv_i[(b*NB + j)*ND + lane];
    }
    erp[w][lane] = er; erp[4 + w][lane] = ei;
    __syncthreads();

    // ---- epilogue: est_latent + p = ef * el (into LDS) ----
    if (tid < ND) {
        const int d = tid;
        const float err = erp[0][d] + erp[1][d] + erp[2][d] + erp[3][d];
        const float eii = erp[4][d] + erp[5][d] + erp[6][d] + erp[7][d];
        const float efr = efr_s[d], efi = efi_s[d];
        const float estr = efr*err - efi*eii;
        const float esti = efr*eii + efi*err;
        const float eta  = 1.0f / (1.0f + expf(-eta_param[d]));
        const float g    = 1.0f / (1.0f + expf(-eta));
        const float vr   = Vr[bi*ND + d], vi = Vi[bi*ND + d];
        const float elr  = (1.0f - eta)*vr + g*estr;
        const float eli  = (1.0f - eta)*vi + g*esti;
        estl_out[((b*2 + 0)*NB + i)*ND + d] = elr;
        estl_out[((b*2 + 1)*NB + i)*ND + d] = eli;
        pr_s[d] = efr*elr - efi*eli;
        pi_s[d] = efr*eli + efi*elr;
    }
    __syncthreads();

    // ---- fused output projection: 4 waves split the e-loop ----
    {
        float po_r = 0.0f, po_i = 0.0f;
        const float* __restrict__ W0 = &Wp_w[lane*ND];
        const float* __restrict__ W1 = &Wp_w[ND*ND + lane*ND];
        const int e0 = w * (ND/4);
        #pragma unroll 4
        for (int e = e0; e < e0 + ND/4; ++e) {
            const float w0 = W0[e], w1 = W1[e];
            po_r += pr_s[e]*w0 - pi_s[e]*w1;
            po_i += pr_s[e]*w1 + pi_s[e]*w0;
        }
        erp[w][lane] = po_r; erp[4 + w][lane] = po_i;
    }
    __syncthreads();
    if (tid < ND) {
        const int d = tid;
        const float orr = Wp_b[d]      + erp[0][d] + erp[1][d] + erp[2][d] + erp[3][d];
        const float oii = Wp_b[ND + d] + erp[4][d] + erp[5][d] + erp[6][d] + erp[7][d];
        out_proj[((b*2 + 0)*NB + i)*ND + d] = orr;
        out_proj[((b*2 + 1)*NB + i)*ND + d] = oii;
    }

    // ---- Z_ij_hat_all stream for this i (all j), nontemporal stores ----
    const int d0    = (tid * 4) & (ND - 1);   // float4 offset within row
    const int jbase = (tid * 4) >> 6;         // 0..15
    const float4 er4 = *(const float4*)&efr_s[d0];
    const float4 ei4 = *(const float4*)&efi_s[d0];

    const size_t base_r = ((size_t)(b*2 + 0)*NB + i) * (size_t)(NB*ND);
    const size_t base_i = ((size_t)(b*2 + 1)*NB + i) * (size_t)(NB*ND);
    const float* __restrict__ UvrB = &Uv_r[(size_t)(b*NB)*ND + d0];
    const float* __restrict__ UviB = &Uv_i[(size_t)(b*NB)*ND + d0];

    #pragma unroll 2
    for (int jg = 0; jg < NB; jg += 16) {
        const int j = jg + jbase;
        const float4 uvr = *(const float4*)&UvrB[(size_t)j*ND];
        const float4 uvi = *(const float4*)&UviB[(size_t)j*ND];
        v4f zr, zi;
        zr.x = er4.x*uvr.x - ei4.x*uvi.x;  zi.x = er4.x*uvi.x + ei4.x*uvr.x;
        zr.y = er4.y*uvr.y - ei4.y*uvi.y;  zi.y = er4.y*uvi.y + ei4.y*uvr.y;
        zr.z = er4.z*uvr.z - ei4.z*uvi.z;  zi.z = er4.z*uvi.z + ei4.z*uvr.z;
        zr.w = er4.w*uvr.w - ei4.w*uvi.w;  zi.w = er4.w*uvi.w + ei4.w*uvr.w;
        const size_t off = (size_t)j*ND + d0;
        __builtin_nontemporal_store(zr, (v4f*)&Z_out[base_r + off]);
        __builtin_nontemporal_store(zi, (v4f*)&Z_out[base_i + off]);
    }
}

extern "C" void kernel_launch(void* const* d_in, const int* in_sizes, int n_in,
                              void* d_out, int out_size, void* d_ws, size_t ws_size,
                              hipStream_t stream) {
    const float* Zq   = (const float*)d_in[0];
    const float* Zk   = (const float*)d_in[1];
    const float* Zv   = (const float*)d_in[2];
    const float* tma  = (const float*)d_in[3];
    const float* Wq_w = (const float*)d_in[4];
    const float* Wq_b = (const float*)d_in[5];
    const float* Wk_w = (const float*)d_in[6];
    const float* Wk_b = (const float*)d_in[7];
    const float* Wv_w = (const float*)d_in[8];
    const float* Wv_b = (const float*)d_in[9];
    const float* Wp_w = (const float*)d_in[10];
    const float* Wp_b = (const float*)d_in[11];
    const float* lamv = (const float*)d_in[12];
    const float* s_lo = (const float*)d_in[13];
    const float* s_lg = (const float*)d_in[14];
    const float* s_nf = (const float*)d_in[15];
    const float* s_tau= (const float*)d_in[16];
    const float* etap = (const float*)d_in[17];

    float* out = (float*)d_out;
    // output offsets (floats), return order: est_latent, out, Q_ij, Z_ij_hat_all, lambda_h
    float* o_est = out;                       // 2*2*512*64   = 131072
    float* o_out = out + 131072;              // 131072
    float* o_Q   = out + 262144;              // 2*2*512*512  = 1048576
    float* o_Z   = out + 1310720;             // 2*2*512*512*64 = 67108864
    float* o_lam = out + 68419584;            // 128

    // workspace layout (floats)
    float* ws   = (float*)d_ws;
    float* ef_r = ws;            // 32768
    float* ef_i = ws + 32768;
    float* Uq_r = ws + 65536;    // each 65536
    float* Uq_i = ws + 131072;
    float* Uk_r = ws + 196608;
    float* Uk_i = ws + 262144;
    float* Uv_r = ws + 327680;
    float* Uv_i = ws + 393216;
    float* Vr   = ws + 458752;
    float* Vi   = ws + 524288;
    float* sumq = ws + 589824;   // 1024
    float* sumk = ws + 590848;   // 1024

    proj_kernel<<<2*NB, 64, 0, stream>>>(Zq, Zk, Zv, tma, Wq_w, Wq_b, Wk_w, Wk_b,
        Wv_w, Wv_b, lamv, ef_r, ef_i, Uq_r, Uq_i, Uk_r, Uk_i, Uv_r, Uv_i,
        Vr, Vi, sumq, sumk, o_lam);

    attn_fused_kernel<<<2*NB, 256, 0, stream>>>(ef_r, ef_i, Uq_r, Uq_i, Uk_r, Uk_i,
        Uv_r, Uv_i, Vr, Vi, sumq, sumk, tma, etap, Wp_w, Wp_b,
        s_lo, s_lg, s_nf, s_tau, o_est, o_out, o_Q, o_Z);
}

// Round 4
// 338.164 us; speedup vs baseline: 1.1023x; 1.1023x over previous
//
#include <hip/hip_runtime.h>
#include <math.h>

#define NB 512
#define ND 64
#define EPSF 1e-8f

typedef float v4f __attribute__((ext_vector_type(4)));

// ---------------- Kernel 1: phases + complex linear projections ----------------
__global__ __launch_bounds__(64) void proj_kernel(
    const float* __restrict__ Zq, const float* __restrict__ Zk, const float* __restrict__ Zv,
    const float* __restrict__ tma,
    const float* __restrict__ Wq_w, const float* __restrict__ Wq_b,
    const float* __restrict__ Wk_w, const float* __restrict__ Wk_b,
    const float* __restrict__ Wv_w, const float* __restrict__ Wv_b,
    const float* __restrict__ lam_v,
    float* __restrict__ ef_r, float* __restrict__ ef_i,
    float* __restrict__ Uq_r, float* __restrict__ Uq_i,
    float* __restrict__ Uk_r, float* __restrict__ Uk_i,
    float* __restrict__ Uv_r, float* __restrict__ Uv_i,
    float* __restrict__ Vr_o, float* __restrict__ Vi_o,
    float* __restrict__ sumq, float* __restrict__ sumk,
    float* __restrict__ lam_out)
{
    const int bn = blockIdx.x;          // b*N + n
    const int b  = bn >> 9;
    const int n  = bn & (NB - 1);
    const int d  = threadIdx.x;         // 0..63

    __shared__ float zqr[ND], zqi[ND], zkr[ND], zki[ND], zvr[ND], zvi[ND];
    zqr[d] = Zq[((b*2 + 0)*NB + n)*ND + d];
    zqi[d] = Zq[((b*2 + 1)*NB + n)*ND + d];
    zkr[d] = Zk[((b*2 + 0)*NB + n)*ND + d];
    zki[d] = Zk[((b*2 + 1)*NB + n)*ND + d];
    zvr[d] = Zv[((b*2 + 0)*NB + n)*ND + d];
    zvi[d] = Zv[((b*2 + 1)*NB + n)*ND + d];
    __syncthreads();

    // lam_imag = concat([lam_v, -lam_v])
    const float lam = (d < 32) ? lam_v[d] : -lam_v[d - 32];
    const float t0    = tma[0];
    const float denom = tma[NB - 1] - t0;
    const float tn    = tma[n] / denom;
    const float ph  = tn * lam;
    const float efr = cosf(ph);
    const float efi = sinf(ph);

    if (b == 0) { ef_r[n*ND + d] = efr; ef_i[n*ND + d] = efi; }
    if (bn == 0) { lam_out[d] = 0.0f; lam_out[ND + d] = lam; }

    float qr = Wq_b[d], qi = Wq_b[ND + d];
    float kr = Wk_b[d], ki = Wk_b[ND + d];
    float vr = Wv_b[d], vi = Wv_b[ND + d];
    const int r0 = d * ND;          // W[0][d][:]
    const int r1 = ND*ND + d * ND;  // W[1][d][:]
    const float4* __restrict__ wq0 = (const float4*)&Wq_w[r0];
    const float4* __restrict__ wq1 = (const float4*)&Wq_w[r1];
    const float4* __restrict__ wk0 = (const float4*)&Wk_w[r0];
    const float4* __restrict__ wk1 = (const float4*)&Wk_w[r1];
    const float4* __restrict__ wv0 = (const float4*)&Wv_w[r0];
    const float4* __restrict__ wv1 = (const float4*)&Wv_w[r1];
    #pragma unroll 4
    for (int e4 = 0; e4 < ND/4; ++e4) {
        const int e = e4 * 4;
        const float4 q0 = wq0[e4], q1 = wq1[e4];
        const float4 k0 = wk0[e4], k1 = wk1[e4];
        const float4 v0 = wv0[e4], v1 = wv1[e4];
        const float zr0 = zqr[e],   zi0 = zqi[e];
        const float zr1 = zqr[e+1], zi1 = zqi[e+1];
        const float zr2 = zqr[e+2], zi2 = zqi[e+2];
        const float zr3 = zqr[e+3], zi3 = zqi[e+3];
        qr += zr0*q0.x - zi0*q1.x;  qi += zr0*q1.x + zi0*q0.x;
        qr += zr1*q0.y - zi1*q1.y;  qi += zr1*q1.y + zi1*q0.y;
        qr += zr2*q0.z - zi2*q1.z;  qi += zr2*q1.z + zi2*q0.z;
        qr += zr3*q0.w - zi3*q1.w;  qi += zr3*q1.w + zi3*q0.w;
        const float yr0 = zkr[e],   yi0 = zki[e];
        const float yr1 = zkr[e+1], yi1 = zki[e+1];
        const float yr2 = zkr[e+2], yi2 = zki[e+2];
        const float yr3 = zkr[e+3], yi3 = zki[e+3];
        kr += yr0*k0.x - yi0*k1.x;  ki += yr0*k1.x + yi0*k0.x;
        kr += yr1*k0.y - yi1*k1.y;  ki += yr1*k1.y + yi1*k0.y;
        kr += yr2*k0.z - yi2*k1.z;  ki += yr2*k1.z + yi2*k0.z;
        kr += yr3*k0.w - yi3*k1.w;  ki += yr3*k1.w + yi3*k0.w;
        const float xr0 = zvr[e],   xi0 = zvi[e];
        const float xr1 = zvr[e+1], xi1 = zvi[e+1];
        const float xr2 = zvr[e+2], xi2 = zvi[e+2];
        const float xr3 = zvr[e+3], xi3 = zvi[e+3];
        vr += xr0*v0.x - xi0*v1.x;  vi += xr0*v1.x + xi0*v0.x;
        vr += xr1*v0.y - xi1*v1.y;  vi += xr1*v1.y + xi1*v0.y;
        vr += xr2*v0.z - xi2*v1.z;  vi += xr2*v1.z + xi2*v0.z;
        vr += xr3*v0.w - xi3*v1.w;  vi += xr3*v1.w + xi3*v0.w;
    }

    // U = conj(ef) * X   (eb = ef_r, -ef_i)
    const float uqr = efr*qr + efi*qi, uqi = efr*qi - efi*qr;
    const float ukr = efr*kr + efi*ki, uki = efr*ki - efi*kr;
    const float uvr = efr*vr + efi*vi, uvi = efr*vi - efi*vr;

    const int idx = bn*ND + d;
    Uq_r[idx] = uqr; Uq_i[idx] = uqi;
    Uk_r[idx] = ukr; Uk_i[idx] = uki;
    Uv_r[idx] = uvr; Uv_i[idx] = uvi;
    Vr_o[idx] = vr;  Vi_o[idx] = vi;

    // per-row |Uq|^2, |Uk|^2 sums (W2 = cos^2+sin^2 == 1)
    float q2 = uqr*uqr + uqi*uqi;
    float k2 = ukr*ukr + uki*uki;
    #pragma unroll
    for (int off = 32; off > 0; off >>= 1) {
        q2 += __shfl_down(q2, off);
        k2 += __shfl_down(k2, off);
    }
    if (d == 0) { sumq[bn] = q2; sumk[bn] = k2; }
}

// ---------------- Kernel 2: fused attention + out-projection + Z_ij stream ----------------
// Structure (vmcnt discipline: no global LOAD may follow the NT store stream,
// or it would force a full store drain — all post-PV inputs are pre-staged):
//  1. stage q/ef/Wp(LDS, padded) + preload V/eta/Wp_b (regs)
//  2. scores + wave-shuffle softmax (6 barriers total)
//  3. Q_out NT store
//  4. FUSED PV + Z loop: one pass over Uv rows — float4/lane loads feed both
//     the PV accumulator and the NT Z-store stream (stores interleave with
//     loads/FMAs, drain under compute; Uv read once instead of twice)
//  5. epilogue: est_latent, out-projection entirely from LDS/regs
__global__ __launch_bounds__(256) void attn_fused_kernel(
    const float* __restrict__ ef_r, const float* __restrict__ ef_i,
    const float* __restrict__ Uq_r, const float* __restrict__ Uq_i,
    const float* __restrict__ Uk_r, const float* __restrict__ Uk_i,
    const float* __restrict__ Uv_r, const float* __restrict__ Uv_i,
    const float* __restrict__ Vr,  const float* __restrict__ Vi,
    const float* __restrict__ sumq, const float* __restrict__ sumk,
    const float* __restrict__ tma,
    const float* __restrict__ eta_param,
    const float* __restrict__ Wp_w, const float* __restrict__ Wp_b,
    const float* __restrict__ s_lo, const float* __restrict__ s_lg,
    const float* __restrict__ s_nf, const float* __restrict__ s_tau,
    float* __restrict__ estl_out,   // est_latent
    float* __restrict__ out_proj,   // out
    float* __restrict__ Q_out,      // Q_ij
    float* __restrict__ Z_out)      // Z_ij_hat_all (256 MB stream)
{
    const int bi   = blockIdx.x;     // b*N + i
    const int b    = bi >> 9;
    const int i    = bi & (NB - 1);
    const int tid  = threadIdx.x;    // 0..255
    const int lane = tid & 63;
    const int w    = tid >> 6;
    const int sub  = lane >> 4;      // 0..3
    const int d4   = (lane & 15) * 4;

    __shared__ __align__(16) float sA[NB];
    __shared__ __align__(16) float qr_s[ND], qi_s[ND];
    __shared__ __align__(16) float efr_s[ND], efi_s[ND];
    __shared__ float redmax[4], redsum[4];
    __shared__ __align__(16) float erpr[4][ND], erpi[4][ND];
    __shared__ __align__(16) float pr_s[ND], pi_s[ND];
    __shared__ float wp_s[2][ND][ND + 1];   // +1 pad: kills bank conflict on [*][lane][e]

    const float t0    = tma[0];
    const float denom = tma[NB - 1] - t0;
    const float ti    = tma[i] / denom;
    const float lo    = s_lo[0] * s_lo[0];
    const float lg    = s_lg[0] * s_lg[0] + EPSF;
    const float nf2   = s_nf[0] * s_nf[0] + EPSF;
    const float tau2  = s_tau[0] * s_tau[0];
    const float t1    = sumq[bi];

    if (tid < ND) {
        qr_s[tid] = Uq_r[bi*ND + tid]; qi_s[tid] = Uq_i[bi*ND + tid];
    } else if (tid < 2*ND) {
        const int d = tid - ND;
        efr_s[d] = ef_r[i*ND + d]; efi_s[d] = ef_i[i*ND + d];
    }
    // stage Wp into LDS (8192 floats, 32/thread)
    for (int idx = tid; idx < 2*ND*ND; idx += 256) {
        const int pl = idx >> 12;
        const int rr = (idx >> 6) & (ND - 1);
        const int cc = idx & (ND - 1);
        wp_s[pl][rr][cc] = Wp_w[idx];
    }
    // preload per-d registers (no global loads allowed after the store stream)
    float vr_reg = 0.f, vi_reg = 0.f, eta_raw = 0.f, wb0 = 0.f, wb1 = 0.f;
    if (tid < ND) {
        vr_reg  = Vr[bi*ND + tid];
        vi_reg  = Vi[bi*ND + tid];
        eta_raw = eta_param[tid];
        wb0     = Wp_b[tid];
        wb1     = Wp_b[ND + tid];
    }
    __syncthreads();

    // ---- scores for j <= i ----
    float lmax = -INFINITY;
    for (int j = tid; j <= i; j += 256) {
        const float4* kr4 = (const float4*)&Uk_r[(b*NB + j)*ND];
        const float4* ki4 = (const float4*)&Uk_i[(b*NB + j)*ND];
        const float4* qr4 = (const float4*)qr_s;
        const float4* qi4 = (const float4*)qi_s;
        float dot = 0.0f;
        #pragma unroll
        for (int e = 0; e < ND/4; ++e) {
            const float4 kr = kr4[e], ki = ki4[e];
            const float4 qr = qr4[e], qi = qi4[e];
            dot += qr.x*kr.x + qr.y*kr.y + qr.z*kr.z + qr.w*kr.w
                 + qi.x*ki.x + qi.y*ki.y + qi.z*ki.z + qi.w*ki.w;
        }
        const float tj   = tma[j] / denom;
        const float vavg = lo * fabsf(ti - tj) + lg;
        const float base = nf2 * vavg + t1 + sumk[b*NB + j] - 2.0f*dot;
        const float sc   = -tau2 * logf(base);
        sA[j] = sc;
        lmax = fmaxf(lmax, sc);
    }

    // ---- block max via wave butterfly + tiny LDS step ----
    #pragma unroll
    for (int m = 1; m < 64; m <<= 1) lmax = fmaxf(lmax, __shfl_xor(lmax, m));
    if (lane == 0) redmax[w] = lmax;
    __syncthreads();
    const float mm = fmaxf(fmaxf(redmax[0], redmax[1]), fmaxf(redmax[2], redmax[3]));

    // ---- exp + block sum (same j-mapping as score loop: no barrier needed) ----
    float lsum = 0.0f;
    for (int j = tid; j <= i; j += 256) {
        const float e = expf(sA[j] - mm);
        sA[j] = e;
        lsum += e;
    }
    #pragma unroll
    for (int m = 1; m < 64; m <<= 1) lsum += __shfl_xor(lsum, m);
    if (lane == 0) redsum[w] = lsum;
    __syncthreads();
    const float inv = 1.0f / (redsum[0] + redsum[1] + redsum[2] + redsum[3]);

    // ---- normalize (zero tail) + write A row + zero imag plane (NT) ----
    for (int j = tid; j < NB; j += 256) {
        float a = 0.0f;
        if (j <= i) a = sA[j] * inv;
        sA[j] = a;
        __builtin_nontemporal_store(a,    &Q_out[((size_t)(b*2 + 0)*NB + i)*NB + j]);
        __builtin_nontemporal_store(0.0f, &Q_out[((size_t)(b*2 + 1)*NB + i)*NB + j]);
    }
    __syncthreads();

    // ---- FUSED PV + Z pass: one float4/lane sweep over all Uv rows ----
    // wave w, sub s handles rows j = 16k + 4w + s; 16 lanes cover d=0..63.
    const float4 efr4 = *(const float4*)&efr_s[d4];
    const float4 efi4 = *(const float4*)&efi_s[d4];
    float erx = 0.f, ery = 0.f, erz = 0.f, erw = 0.f;
    float eix = 0.f, eiy = 0.f, eiz = 0.f, eiw = 0.f;
    const size_t base_r = ((size_t)(b*2 + 0)*NB + i) * (size_t)(NB*ND);
    const size_t base_i = ((size_t)(b*2 + 1)*NB + i) * (size_t)(NB*ND);
    const float* __restrict__ UvrB = &Uv_r[(size_t)(b*NB)*ND];
    const float* __restrict__ UviB = &Uv_i[(size_t)(b*NB)*ND];
    const int j0 = 4*w + sub;

    #pragma unroll 4
    for (int k = 0; k < NB/16; ++k) {
        const int j = 16*k + j0;
        const size_t roff = (size_t)j*ND + d4;
        const float4 uvr = *(const float4*)&UvrB[roff];
        const float4 uvi = *(const float4*)&UviB[roff];
        v4f zr, zi;
        zr.x = efr4.x*uvr.x - efi4.x*uvi.x;  zi.x = efr4.x*uvi.x + efi4.x*uvr.x;
        zr.y = efr4.y*uvr.y - efi4.y*uvi.y;  zi.y = efr4.y*uvi.y + efi4.y*uvr.y;
        zr.z = efr4.z*uvr.z - efi4.z*uvi.z;  zi.z = efr4.z*uvi.z + efi4.z*uvr.z;
        zr.w = efr4.w*uvr.w - efi4.w*uvi.w;  zi.w = efr4.w*uvi.w + efi4.w*uvr.w;
        __builtin_nontemporal_store(zr, (v4f*)&Z_out[base_r + roff]);
        __builtin_nontemporal_store(zi, (v4f*)&Z_out[base_i + roff]);
        const float a = sA[j];   // 0 for j > i (zeroed above); broadcast read
        erx += a*uvr.x; ery += a*uvr.y; erz += a*uvr.z; erw += a*uvr.w;
        eix += a*uvi.x; eiy += a*uvi.y; eiz += a*uvi.z; eiw += a*uvi.w;
    }

    // combine the 4 sub-phases (lanes l, l^16, l^32, l^48 share the same d-range)
    #pragma unroll
    for (int m = 16; m < 64; m <<= 1) {
        erx += __shfl_xor(erx, m); ery += __shfl_xor(ery, m);
        erz += __shfl_xor(erz, m); erw += __shfl_xor(erw, m);
        eix += __shfl_xor(eix, m); eiy += __shfl_xor(eiy, m);
        eiz += __shfl_xor(eiz, m); eiw += __shfl_xor(eiw, m);
    }
    if (lane < 16) {
        float4 er4; er4.x = erx; er4.y = ery; er4.z = erz; er4.w = erw;
        float4 ei4; ei4.x = eix; ei4.y = eiy; ei4.z = eiz; ei4.w = eiw;
        *(float4*)&erpr[w][lane*4] = er4;
        *(float4*)&erpi[w][lane*4] = ei4;
    }
    __syncthreads();

    // ---- epilogue: est_latent + p = ef * el (LDS/regs only) ----
    if (tid < ND) {
        const int d = tid;
        const float err = erpr[0][d] + erpr[1][d] + erpr[2][d] + erpr[3][d];
        const float eii = erpi[0][d] + erpi[1][d] + erpi[2][d] + erpi[3][d];
        const float efr = efr_s[d], efi = efi_s[d];
        const float estr = efr*err - efi*eii;
        const float esti = efr*eii + efi*err;
        const float eta  = 1.0f / (1.0f + expf(-eta_raw));
        const float g    = 1.0f / (1.0f + expf(-eta));
        const float elr  = (1.0f - eta)*vr_reg + g*estr;
        const float eli  = (1.0f - eta)*vi_reg + g*esti;
        estl_out[((b*2 + 0)*NB + i)*ND + d] = elr;
        estl_out[((b*2 + 1)*NB + i)*ND + d] = eli;
        pr_s[d] = efr*elr - efi*eli;
        pi_s[d] = efr*eli + efi*elr;
    }
    __syncthreads();

    // ---- fused output projection from LDS-staged Wp (4 waves split e) ----
    {
        float po_r = 0.0f, po_i = 0.0f;
        const int e0 = w * (ND/4);
        #pragma unroll 4
        for (int e = e0; e < e0 + ND/4; ++e) {
            const float w0 = wp_s[0][lane][e], w1 = wp_s[1][lane][e];
            po_r += pr_s[e]*w0 - pi_s[e]*w1;
            po_i += pr_s[e]*w1 + pi_s[e]*w0;
        }
        erpr[w][lane] = po_r; erpi[w][lane] = po_i;
    }
    __syncthreads();
    if (tid < ND) {
        const int d = tid;
        const float orr = wb0 + erpr[0][d] + erpr[1][d] + erpr[2][d] + erpr[3][d];
        const float oii = wb1 + erpi[0][d] + erpi[1][d] + erpi[2][d] + erpi[3][d];
        out_proj[((b*2 + 0)*NB + i)*ND + d] = orr;
        out_proj[((b*2 + 1)*NB + i)*ND + d] = oii;
    }
}

extern "C" void kernel_launch(void* const* d_in, const int* in_sizes, int n_in,
                              void* d_out, int out_size, void* d_ws, size_t ws_size,
                              hipStream_t stream) {
    const float* Zq   = (const float*)d_in[0];
    const float* Zk   = (const float*)d_in[1];
    const float* Zv   = (const float*)d_in[2];
    const float* tma  = (const float*)d_in[3];
    const float* Wq_w = (const float*)d_in[4];
    const float* Wq_b = (const float*)d_in[5];
    const float* Wk_w = (const float*)d_in[6];
    const float* Wk_b = (const float*)d_in[7];
    const float* Wv_w = (const float*)d_in[8];
    const float* Wv_b = (const float*)d_in[9];
    const float* Wp_w = (const float*)d_in[10];
    const float* Wp_b = (const float*)d_in[11];
    const float* lamv = (const float*)d_in[12];
    const float* s_lo = (const float*)d_in[13];
    const float* s_lg = (const float*)d_in[14];
    const float* s_nf = (const float*)d_in[15];
    const float* s_tau= (const float*)d_in[16];
    const float* etap = (const float*)d_in[17];

    float* out = (float*)d_out;
    // output offsets (floats), return order: est_latent, out, Q_ij, Z_ij_hat_all, lambda_h
    float* o_est = out;                       // 2*2*512*64   = 131072
    float* o_out = out + 131072;              // 131072
    float* o_Q   = out + 262144;              // 2*2*512*512  = 1048576
    float* o_Z   = out + 1310720;             // 2*2*512*512*64 = 67108864
    float* o_lam = out + 68419584;            // 128

    // workspace layout (floats)
    float* ws   = (float*)d_ws;
    float* ef_r = ws;            // 32768
    float* ef_i = ws + 32768;
    float* Uq_r = ws + 65536;    // each 65536
    float* Uq_i = ws + 131072;
    float* Uk_r = ws + 196608;
    float* Uk_i = ws + 262144;
    float* Uv_r = ws + 327680;
    float* Uv_i = ws + 393216;
    float* Vr   = ws + 458752;
    float* Vi   = ws + 524288;
    float* sumq = ws + 589824;   // 1024
    float* sumk = ws + 590848;   // 1024

    proj_kernel<<<2*NB, 64, 0, stream>>>(Zq, Zk, Zv, tma, Wq_w, Wq_b, Wk_w, Wk_b,
        Wv_w, Wv_b, lamv, ef_r, ef_i, Uq_r, Uq_i, Uk_r, Uk_i, Uv_r, Uv_i,
        Vr, Vi, sumq, sumk, o_lam);

    attn_fused_kernel<<<2*NB, 256, 0, stream>>>(ef_r, ef_i, Uq_r, Uq_i, Uk_r, Uk_i,
        Uv_r, Uv_i, Vr, Vi, sumq, sumk, tma, etap, Wp_w, Wp_b,
        s_lo, s_lg, s_nf, s_tau, o_est, o_out, o_Q, o_Z);
}